// Round 13
// baseline (89.035 us; speedup 1.0000x reference)
//
#include <hip/hip_runtime.h>
#include <math.h>
#include <stdint.h>

typedef unsigned short u16;
typedef short v8s __attribute__((ext_vector_type(8)));
typedef float v4f __attribute__((ext_vector_type(4)));

constexpr int kT   = 2048;
constexpr int kHID = 1024;
constexpr int kH   = 16;
constexpr int kNB  = 32;
constexpr size_t MB = 1ull << 20;

__device__ __forceinline__ float b2f(u16 u) { unsigned x = ((unsigned)u) << 16; return __uint_as_float(x); }
__device__ __forceinline__ u16 f2b(float f) {
  unsigned x = __float_as_uint(f);
  x += 0x7FFFu + ((x >> 16) & 1u);
  return (u16)(x >> 16);
}
__device__ __forceinline__ v4f mfma16(v8s a, v8s b, v4f c) {
  return __builtin_amdgcn_mfma_f32_16x16x32_bf16(a, b, c, 0, 0, 0);
}
__device__ __forceinline__ void gl_lds16(const void* g, void* l) {
  __builtin_amdgcn_global_load_lds((const __attribute__((address_space(1))) uint32_t*)g,
                                   (__attribute__((address_space(3))) uint32_t*)l, 16, 0, 0);
}

// ==== fused prep: x->bf16, Wq/Wk/Wv/Wo transposes, Wc transpose hi/lo, Ws pad(128) ====
__global__ __launch_bounds__(256) void prep_kernel(
    const float* __restrict__ x, const float* __restrict__ Wq, const float* __restrict__ Wk,
    const float* __restrict__ Wv, const float* __restrict__ Wo, const float* __restrict__ Wc,
    const float* __restrict__ Wsp,
    u16* __restrict__ xh,
    u16* __restrict__ WqtH, u16* __restrict__ WktH,
    u16* __restrict__ WvtH, u16* __restrict__ WotH, u16* __restrict__ WctH, u16* __restrict__ WctL,
    u16* __restrict__ Wst) {
  __shared__ float tbuf[32][33];
  int bid = blockIdx.x;
  const int tid = threadIdx.x;
  if (bid < 1024) {                        // x -> bf16: 8 elems/thread
    int i = bid * 2048 + tid * 8;
    float4 a = *(const float4*)(x + i), b = *(const float4*)(x + i + 4);
    float tv[8] = {a.x, a.y, a.z, a.w, b.x, b.y, b.z, b.w};
    union { u16 s[8]; uint4 u; } hs;
#pragma unroll
    for (int e = 0; e < 8; ++e) hs.s[e] = f2b(tv[e]);
    *(uint4*)(xh + i) = hs.u;
    return;
  }
  bid -= 1024;
  const float* W; u16* Hh; u16* Ll; int Kd, Nd, bx, by;
  if (bid < 4096) {                        // 1024x1024 weight transposes
    int wsel = bid >> 10, sub = bid & 1023;
    W  = wsel == 0 ? Wq : wsel == 1 ? Wk : wsel == 2 ? Wv : Wo;
    Hh = wsel == 0 ? WqtH : wsel == 1 ? WktH : wsel == 2 ? WvtH : WotH;
    Ll = nullptr;
    Kd = 1024; Nd = 1024;
    bx = (sub & 31) * 32; by = (sub >> 5) * 32;
  } else if (bid < 4096 + 256) {           // Wc (4096x64), hi/lo
    int sub = bid - 4096;
    W = Wc; Hh = WctH; Ll = WctL;
    Kd = 4096; Nd = 64;
    bx = (sub & 1) * 32; by = (sub >> 1) * 32;
  } else {                                 // Wst pad: 128x1024
    int i = (bid - 4096 - 256) * 256 + tid;
    int n = i >> 10, k2 = i & 1023;
    float v = (n < 48) ? Wsp[(size_t)k2 * 48 + n] : 0.f;
    Wst[(size_t)n * 1024 + k2] = f2b(v);
    return;
  }
  const int lx = tid & 31, ly = tid >> 5;
  for (int i2 = ly; i2 < 32; i2 += 8) tbuf[i2][lx] = W[(size_t)(by + i2) * Nd + bx + lx];
  __syncthreads();
  for (int i2 = ly; i2 < 32; i2 += 8) {
    float xv = tbuf[lx][i2];
    size_t idx = (size_t)(bx + i2) * Kd + by + lx;
    u16 h = f2b(xv);
    Hh[idx] = h;
    if (Ll) Ll[idx] = f2b(xv - b2f(h));
  }
}

// ==== unified projection GEMM, single-combo bf16, BM=64 BN=128 BK=64 ====
__global__ __launch_bounds__(256) void proj_gemm(const u16* __restrict__ xh,
                                                 const u16* __restrict__ WkH, const u16* __restrict__ WqH,
                                                 const u16* __restrict__ WvH, const u16* __restrict__ Wst,
                                                 const float* __restrict__ bsp,
                                                 u16* __restrict__ kbf, u16* __restrict__ qh,
                                                 u16* __restrict__ vbf, float* __restrict__ strat) {
  __shared__ u16 AsH[64 * 64], BsH[128 * 64];   // 24 KB
  const int b = blockIdx.x;                      // 800 blocks
  const int slot = (b & 7) * 100 + (b >> 3);     // bijective [0,800)
  const int panel = slot >> 5, bmi = slot & 31;
  int z, bni;
  if (panel < 8)       { z = 0; bni = panel; }
  else if (panel < 16) { z = 1; bni = panel - 8; }
  else if (panel < 24) { z = 2; bni = panel - 16; }
  else                 { z = 3; bni = 0; }
  const int bm = bmi * 64, bn = bni * 128;
  const u16* Bh = (z == 0) ? WkH : (z == 1) ? WqH : (z == 2) ? WvH : Wst;
  const int tid = threadIdx.x, w = tid >> 6, lane = tid & 63;
  const int lg = lane >> 4, l16 = lane & 15;
  const int wr = w >> 1, wc = w & 1;
  v4f acc[2][4] = {};
  for (int k0 = 0; k0 < kHID; k0 += 64) {
    __syncthreads();
#pragma unroll
    for (int p = 0; p < 2; ++p) {
      int s = tid + p * 256, row = s >> 3, sf = (s & 7) ^ (row & 7);
      gl_lds16(xh + (size_t)(bm + row) * kHID + k0 + sf * 8, (char*)AsH + s * 16);
    }
#pragma unroll
    for (int p = 0; p < 4; ++p) {
      int s = tid + p * 256, row = s >> 3, sf = (s & 7) ^ (row & 7);
      gl_lds16(Bh + (size_t)(bn + row) * kHID + k0 + sf * 8, (char*)BsH + s * 16);
    }
    __syncthreads();
#pragma unroll
    for (int kk = 0; kk < 2; ++kk) {
      v8s bh4[4];
#pragma unroll
      for (int j = 0; j < 4; ++j) {
        int col = wc * 64 + j * 16 + l16;
        bh4[j] = *(const v8s*)((const char*)BsH + col * 128 + (((kk * 4 + lg) ^ (col & 7)) * 16));
      }
#pragma unroll
      for (int i = 0; i < 2; ++i) {
        int row = wr * 32 + i * 16 + l16;
        v8s ah = *(const v8s*)((const char*)AsH + row * 128 + (((kk * 4 + lg) ^ (row & 7)) * 16));
#pragma unroll
        for (int j = 0; j < 4; ++j) acc[i][j] = mfma16(ah, bh4[j], acc[i][j]);
      }
    }
  }
#pragma unroll
  for (int i = 0; i < 2; ++i)
#pragma unroll
    for (int j = 0; j < 4; ++j)
#pragma unroll
      for (int r = 0; r < 4; ++r) {
        int row = bm + wr * 32 + i * 16 + lg * 4 + r;
        int col = bn + wc * 64 + j * 16 + l16;
        float val = acc[i][j][r];
        if (z == 3) {
          if (col < 48) strat[(size_t)row * 48 + col] = 1.f / (1.f + expf(-(val + bsp[col])));
        } else {
          u16 hh = f2b(val);
          size_t idx = (size_t)row * kHID + col;
          if (z == 0) kbf[idx] = hh;
          else if (z == 1) qh[idx] = hh;
          else vbf[idx] = hh;
        }
      }
}

// ==== compress GEMM: K-path 2-combo (k·WcH + k·WcL), V-path single; split-K partials ====
__global__ __launch_bounds__(256) void cgemm_fused(const u16* __restrict__ kbf,
                                                   const u16* __restrict__ vbf,
                                                   const u16* __restrict__ WcH, const u16* __restrict__ WcL,
                                                   float* __restrict__ Pk, float* __restrict__ Pv) {
  __shared__ u16 AsH[64 * 64], BsH[64 * 64], BsL[64 * 64];   // 24 KB
  const int bm = blockIdx.y * 64;
  const int isK = (blockIdx.z < 8);
  const int ks = isK ? blockIdx.z : blockIdx.z - 8;
  const u16* Asrc = isK ? kbf : vbf;
  float* P = isK ? Pk : Pv;
  const int tid = threadIdx.x;
  const int w = tid >> 6, lane = tid & 63;
  const int lg = lane >> 4, l16 = lane & 15;
  const int wr = w >> 1, wc = w & 1;
  v4f acc[2][2] = {};
  for (int k0 = ks * 512; k0 < ks * 512 + 512; k0 += 64) {
    __syncthreads();
#pragma unroll
    for (int ss = 0; ss < 2; ++ss) {
      int s = tid + ss * 256, row = s >> 3, sf = (s & 7) ^ (row & 7);
      int r = bm + row;                              // (h*32+nb)
      size_t abase = ((size_t)((r & 31) * 64 + (k0 >> 6))) * kHID + (r >> 5) * 64 + sf * 8;
      gl_lds16(Asrc + abase, (char*)AsH + s * 16);
      gl_lds16(WcH + (size_t)row * 4096 + k0 + sf * 8, (char*)BsH + s * 16);
      if (isK) gl_lds16(WcL + (size_t)row * 4096 + k0 + sf * 8, (char*)BsL + s * 16);
    }
    __syncthreads();
    v8s ah[2][2], bh[2][2];
#pragma unroll
    for (int i = 0; i < 2; ++i)
#pragma unroll
      for (int kk = 0; kk < 2; ++kk) {
        int row = wr * 32 + i * 16 + l16;
        ah[i][kk] = *(const v8s*)((const char*)AsH + row * 128 + (((kk * 4 + lg) ^ (row & 7)) * 16));
        int col = wc * 32 + i * 16 + l16;
        bh[i][kk] = *(const v8s*)((const char*)BsH + col * 128 + (((kk * 4 + lg) ^ (col & 7)) * 16));
      }
#pragma unroll
    for (int i = 0; i < 2; ++i)
#pragma unroll
      for (int j = 0; j < 2; ++j) {
        acc[i][j] = mfma16(ah[i][0], bh[j][0], acc[i][j]);
        acc[i][j] = mfma16(ah[i][1], bh[j][1], acc[i][j]);
      }
    if (isK) {
      v8s bl[2][2];
#pragma unroll
      for (int i = 0; i < 2; ++i)
#pragma unroll
        for (int kk = 0; kk < 2; ++kk) {
          int col = wc * 32 + i * 16 + l16;
          bl[i][kk] = *(const v8s*)((const char*)BsL + col * 128 + (((kk * 4 + lg) ^ (col & 7)) * 16));
        }
#pragma unroll
      for (int i = 0; i < 2; ++i)
#pragma unroll
        for (int j = 0; j < 2; ++j) {
          acc[i][j] = mfma16(ah[i][0], bl[j][0], acc[i][j]);
          acc[i][j] = mfma16(ah[i][1], bl[j][1], acc[i][j]);
        }
    }
  }
#pragma unroll
  for (int i = 0; i < 2; ++i)
#pragma unroll
    for (int j = 0; j < 2; ++j)
#pragma unroll
      for (int r = 0; r < 4; ++r) {
        int row = bm + wr * 32 + i * 16 + lg * 4 + r;
        int col = wc * 32 + j * 16 + l16;
        P[(size_t)ks * 32768 + (size_t)row * 64 + col] = acc[i][j][r];
      }
}

// ==== fused attention: reduce+GELU + importance + comp + selection + fine + slide ====
__global__ __launch_bounds__(256) void attn_fused(const u16* __restrict__ qh,
                                                  const u16* __restrict__ kb_,
                                                  const u16* __restrict__ vb_,
                                                  const float* __restrict__ Pk,
                                                  const float* __restrict__ Pv,
                                                  const float* __restrict__ bc,
                                                  const float* __restrict__ strat,
                                                  const float* __restrict__ kscale_p,
                                                  const float* __restrict__ kbias_p,
                                                  float* __restrict__ krb,
                                                  float* __restrict__ neb,
                                                  int* __restrict__ dkb,
                                                  u16* __restrict__ merged) {
  __shared__ char smem[40960] __attribute__((aligned(128)));
  const int b = blockIdx.x;
  const int xcd = b & 7, slot = b >> 3;
  const int h = xcd + 8 * (slot >> 5);     // head-colocated per XCD
  const int qb = slot & 31;
  const int tid = threadIdx.x, w = tid >> 6, lane = tid & 63;
  const int lg = lane >> 4, l16 = lane & 15;

  // ======== phase A: impsel ========
  char* KCH = smem;               // 4 KB
  char* KCL = smem + 4096;        // 4 KB
  char* VCT = smem + 8192;        // 4 KB
  u16*  PlA = (u16*)(smem + 12288);   // 4 KB
  float* red = (float*)(smem + 16384);   // 512 B
  unsigned* mshare = (unsigned*)(smem + 16896);
  {
    int nb = tid >> 3, seg = tid & 7;
    {
      const float* base = Pk + ((size_t)(h * 32 + nb) * 64 + seg * 8);
      float v[8] = {};
#pragma unroll
      for (int ks = 0; ks < 8; ++ks) {
        const float* p = base + (size_t)ks * 32768;
        float4 a = *(const float4*)p, bq = *(const float4*)(p + 4);
        v[0] += a.x; v[1] += a.y; v[2] += a.z; v[3] += a.w;
        v[4] += bq.x; v[5] += bq.y; v[6] += bq.z; v[7] += bq.w;
      }
      v8s hi, lo;
#pragma unroll
      for (int e = 0; e < 8; ++e) {
        float s = v[e] + bc[seg * 8 + e];
        float g = 0.5f * s * (1.f + erff(s * 0.70710678118654752f));
        u16 hh = f2b(g);
        hi[e] = (short)hh;
        lo[e] = (short)f2b(g - b2f(hh));
      }
      *(v8s*)(KCH + nb * 128 + ((seg ^ (nb & 7)) * 16)) = hi;
      *(v8s*)(KCL + nb * 128 + ((seg ^ (nb & 7)) * 16)) = lo;
    }
    {
      const float* base = Pv + ((size_t)(h * 32 + nb) * 64 + seg * 8);
      float v[8] = {};
#pragma unroll
      for (int ks = 0; ks < 8; ++ks) {
        const float* p = base + (size_t)ks * 32768;
        float4 a = *(const float4*)p, bq = *(const float4*)(p + 4);
        v[0] += a.x; v[1] += a.y; v[2] += a.z; v[3] += a.w;
        v[4] += bq.x; v[5] += bq.y; v[6] += bq.z; v[7] += bq.w;
      }
#pragma unroll
      for (int e = 0; e < 8; ++e) {
        int d = seg * 8 + e;
        float s = v[e] + bc[d];
        float g = 0.5f * s * (1.f + erff(s * 0.70710678118654752f));
        *((u16*)(VCT + d * 64 + (((nb >> 3) ^ (d & 3)) * 16) + (nb & 7) * 2)) = f2b(g);
      }
    }
  }
  // prefetch strat gates for epilogue (independent of everything below)
  float st0r[4], st1r[4], st2r[4];
#pragma unroll
  for (int j = 0; j < 4; ++j) {
    int t = qb * 64 + w * 16 + lg * 4 + j;
    st0r[j] = strat[t * 48 + h * 3 + 0];
    st1r[j] = strat[t * 48 + h * 3 + 1];
    st2r[j] = strat[t * 48 + h * 3 + 2];
  }
  __syncthreads();
  const size_t qoff = (size_t)(qb * 64 + w * 16 + l16) * kHID + h * 64;
  v8s aq[2];
  aq[0] = *(const v8s*)(qh + qoff + lg * 8);
  aq[1] = *(const v8s*)(qh + qoff + 32 + lg * 8);
  v4f sa2[2] = {};
#pragma unroll
  for (int ct = 0; ct < 2; ++ct) {
    int col = ct * 16 + l16;
#pragma unroll
    for (int kk = 0; kk < 2; ++kk) {
      int bo = col * 128 + (((kk * 4 + lg) ^ (col & 7)) * 16);
      v8s bh = *(const v8s*)(KCH + bo);
      v8s bl = *(const v8s*)(KCL + bo);
      sa2[ct] = mfma16(aq[kk], bh, sa2[ct]);
      sa2[ct] = mfma16(aq[kk], bl, sa2[ct]);
    }
  }
#pragma unroll
  for (int ct = 0; ct < 2; ++ct)
#pragma unroll
    for (int j = 0; j < 4; ++j) sa2[ct][j] *= 0.125f;
#pragma unroll
  for (int ct = 0; ct < 2; ++ct) {
    float v = sa2[ct][0] + sa2[ct][1] + sa2[ct][2] + sa2[ct][3];
    v += __shfl_xor(v, 16, 64);
    v += __shfl_xor(v, 32, 64);
    if (lg == 0) red[w * 32 + ct * 16 + l16] = v;
  }
  float linv[4];
#pragma unroll
  for (int j = 0; j < 4; ++j) {
    float m = fmaxf(sa2[0][j], sa2[1][j]);
#pragma unroll
    for (int mm = 1; mm < 16; mm <<= 1) m = fmaxf(m, __shfl_xor(m, mm, 64));
    float e0 = __expf(sa2[0][j] - m), e1 = __expf(sa2[1][j] - m);
    float s = e0 + e1;
#pragma unroll
    for (int mm = 1; mm < 16; mm <<= 1) s += __shfl_xor(s, mm, 64);
    linv[j] = 1.f / s;
    int row = lg * 4 + j;
    PlA[w * 512 + row * 32 + l16] = f2b(e0);
    PlA[w * 512 + row * 32 + 16 + l16] = f2b(e1);
  }
  v8s pca = *(const v8s*)(PlA + w * 512 + l16 * 32 + lg * 8);
  float compC[4][4];
  {
    v4f o[4];
#pragma unroll
    for (int dt = 0; dt < 4; ++dt) {
      int d = dt * 16 + l16;
      v8s bb = *(const v8s*)(VCT + d * 64 + ((lg ^ (d & 3)) * 16));
      v4f z = {};
      o[dt] = mfma16(pca, bb, z);
#pragma unroll
      for (int j = 0; j < 4; ++j) compC[dt][j] = o[dt][j] * linv[j];
    }
  }
  __syncthreads();
  // selection by wave 0 -> mword broadcast
  if (w == 0) {
    const int j = lane & 31;
    float bsj = (red[j] + red[32 + j] + red[64 + j] + red[96 + j]) * (1.f / 64.f);
    float mx = bsj;
#pragma unroll
    for (int m = 1; m < 32; m <<= 1) mx = fmaxf(mx, __shfl_xor(mx, m, 64));
    float e = expf(bsj - mx);
    float lsum = e;
#pragma unroll
    for (int m = 1; m < 32; m <<= 1) lsum += __shfl_xor(lsum, m, 64);
    float p = e / lsum;
    float ent = p * logf(p + 1e-9f);
#pragma unroll
    for (int m = 1; m < 32; m <<= 1) ent += __shfl_xor(ent, m, 64);
    ent = -ent;
    float ne = ent / (logf(32.f) + 1e-9f);
    float kr = 1.f / (1.f + expf(-(kscale_p[0] * ne + kbias_p[0])));
    int dk = (int)fminf(fmaxf(8.f * kr, 1.f), 8.f);
    unsigned mword = 1u << qb;
    int taken = 0;
    for (int r = 0; r < dk; ++r) {
      float v2 = taken ? -3.4e38f : bsj;
      int idx2 = j;
#pragma unroll
      for (int m = 1; m < 32; m <<= 1) {
        float ov = __shfl_xor(v2, m, 64);
        int oi = __shfl_xor(idx2, m, 64);
        if (ov > v2 || (ov == v2 && oi < idx2)) { v2 = ov; idx2 = oi; }
      }
      mword |= (1u << idx2);
      if (j == idx2) taken = 1;
    }
    if (lane == 0) {
      krb[h * kNB + qb] = kr;
      neb[h * kNB + qb] = ne;
      dkb[h * kNB + qb] = dk;
      *mshare = mword;
    }
  }
  __syncthreads();
  const unsigned mword = *mshare;
  __syncthreads();   // all reads of phase-A LDS done; arena reusable

  // ======== phase B: fine + slide ========
  char* KbB = smem;            // 2 x 8 KB
  char* VtB = smem + 16384;    // 2 x 8 KB
  char* PlB = smem + 32768;    // 8 KB
  unsigned uni = mword | (1u << qb);
  if (qb > 0) uni |= 1u << (qb - 1);
  float mF[4], lF[4], mS[4], lS[4];
  v4f oF[4] = {}, oS[4] = {};
#pragma unroll
  for (int j = 0; j < 4; ++j) { mF[j] = -1e30f; lF[j] = 0.f; mS[j] = -1e30f; lS[j] = 0.f; }
  const int vkey = tid & 63, vd0 = (tid >> 6) * 16;

  auto k_stage = [&](int buf, int jb) {
#pragma unroll
    for (int ss = 0; ss < 2; ++ss) {
      int s = tid + ss * 256;
      int key = s >> 3, sf = (s & 7) ^ (key & 7);
      gl_lds16(kb_ + (size_t)(jb * 64 + key) * kHID + h * 64 + sf * 8, KbB + buf * 8192 + s * 16);
    }
  };
  auto v_issue = [&](int jb, uint4& c0, uint4& c1) {
    const u16* vsrc = vb_ + (size_t)(jb * 64 + vkey) * kHID + h * 64 + vd0;
    c0 = *(const uint4*)(vsrc);
    c1 = *(const uint4*)(vsrc + 8);
  };
  auto v_write = [&](int buf, uint4 c0, uint4 c1) {
    union { uint4 u[2]; u16 s[16]; } c;
    c.u[0] = c0; c.u[1] = c1;
#pragma unroll
    for (int i = 0; i < 16; ++i) {
      int d = vd0 + i;
      *((u16*)(VtB + buf * 8192 + d * 128 + (((vkey >> 3) ^ (d & 7)) * 16)) + (vkey & 7)) = c.s[i];
    }
  };
  auto upd = [&](const v4f* sa, float* m_run, float* l_run, v4f* o_acc, int buf) {
    float corr[4];
#pragma unroll
    for (int j = 0; j < 4; ++j) {
      float t = fmaxf(fmaxf(sa[0][j], sa[1][j]), fmaxf(sa[2][j], sa[3][j]));
#pragma unroll
      for (int mm = 1; mm < 16; mm <<= 1) t = fmaxf(t, __shfl_xor(t, mm, 64));
      float mn = fmaxf(m_run[j], t);
      corr[j] = __expf(m_run[j] - mn);
      m_run[j] = mn;
    }
    float rs[4] = {0.f, 0.f, 0.f, 0.f};
    float pv[4][4];
#pragma unroll
    for (int ct = 0; ct < 4; ++ct)
#pragma unroll
      for (int j = 0; j < 4; ++j) {
        float e = __expf(sa[ct][j] - m_run[j]);
        pv[ct][j] = e;
        rs[j] += e;
      }
#pragma unroll
    for (int j = 0; j < 4; ++j) {
#pragma unroll
      for (int mm = 1; mm < 16; mm <<= 1) rs[j] += __shfl_xor(rs[j], mm, 64);
      l_run[j] = l_run[j] * corr[j] + rs[j];
    }
#pragma unroll
    for (int ct = 0; ct < 4; ++ct)
#pragma unroll
      for (int j = 0; j < 4; ++j) {
        int row = lg * 4 + j;
        int seg = ct * 2 + (l16 >> 3);
        *((u16*)(PlB + w * 2048 + row * 128 + ((seg ^ (row & 7)) * 16)) + (l16 & 7)) = f2b(pv[ct][j]);
      }
#pragma unroll
    for (int dt = 0; dt < 4; ++dt)
#pragma unroll
      for (int j = 0; j < 4; ++j) o_acc[dt][j] *= corr[j];
    __builtin_amdgcn_s_setprio(1);
#pragma unroll
    for (int dt = 0; dt < 4; ++dt) {
      int d = dt * 16 + l16;
#pragma unroll
      for (int kk = 0; kk < 2; ++kk) {
        v8s pa = *(const v8s*)(PlB + w * 2048 + l16 * 128 + (((kk * 4 + lg) ^ (l16 & 7)) * 16));
        v8s vb2 = *(const v8s*)(VtB + buf * 8192 + d * 128 + (((kk * 4 + lg) ^ (d & 7)) * 16));
        o_acc[dt] = mfma16(pa, vb2, o_acc[dt]);
      }
    }
    __builtin_amdgcn_s_setprio(0);
  };

  int jb_cur = __builtin_ctz(uni);
  unsigned rem = uni & (uni - 1);
  uint4 vc0, vc1;
  v_issue(jb_cur, vc0, vc1);
  k_stage(0, jb_cur);
  v_write(0, vc0, vc1);
  int buf = 0;
  while (jb_cur >= 0) {
    int jb_next = -1;
    if (rem) { jb_next = __builtin_ctz(rem); rem &= rem - 1; }
    __syncthreads();
    if (jb_next >= 0) { v_issue(jb_next, vc0, vc1); k_stage(buf ^ 1, jb_next); }
    v4f sa[4] = {};
    __builtin_amdgcn_s_setprio(1);
#pragma unroll
    for (int ct = 0; ct < 4; ++ct) {
      int key = ct * 16 + l16;
#pragma unroll
      for (int kk = 0; kk < 2; ++kk) {
        v8s bk = *(const v8s*)(KbB + buf * 8192 + key * 128 + (((kk * 4 + lg) ^ (key & 7)) * 16));
        sa[ct] = mfma16(aq[kk], bk, sa[ct]);
      }
    }
    __builtin_amdgcn_s_setprio(0);
#pragma unroll
    for (int ct = 0; ct < 4; ++ct)
#pragma unroll
      for (int j = 0; j < 4; ++j) sa[ct][j] *= 0.125f;
    const bool inF = (mword >> jb_cur) & 1u;
    const bool inS = (jb_cur == qb) || (jb_cur + 1 == qb);
    if (inF) upd(sa, mF, lF, oF, buf);
    if (inS) {
      v4f sb[4];
#pragma unroll
      for (int ct = 0; ct < 4; ++ct) sb[ct] = sa[ct];
      if (jb_cur == qb) {
#pragma unroll
        for (int ct = 0; ct < 4; ++ct) {
          int key = ct * 16 + l16;
#pragma unroll
          for (int j = 0; j < 4; ++j) {
            int qp = w * 16 + lg * 4 + j;
            if (key > qp) sb[ct][j] = -1e30f;
          }
        }
      }
      upd(sb, mS, lS, oS, buf);
    }
    if (jb_next >= 0) v_write(buf ^ 1, vc0, vc1);
    jb_cur = jb_next;
    buf ^= 1;
  }
  // epilogue: merged = st0*slide + st1*comp + st2*fine (single store)
#pragma unroll
  for (int j = 0; j < 4; ++j) {
    int t = qb * 64 + w * 16 + lg * 4 + j;
    float invS = 1.f / lS[j], invF = 1.f / lF[j];
#pragma unroll
    for (int dt = 0; dt < 4; ++dt) {
      int d = dt * 16 + l16;
      size_t idx = (size_t)t * kHID + h * 64 + d;
      float val = st0r[j] * (oS[dt][j] * invS) + st1r[j] * compC[dt][j] + st2r[j] * (oF[dt][j] * invF);
      merged[idx] = f2b(val);
    }
  }
}

// ==== output projection + finalize scalars: BM=64 BN=64, 512 blocks ====
__global__ __launch_bounds__(256) void gemm_out(const u16* __restrict__ A, const u16* __restrict__ Bt,
                                                const float* __restrict__ krb, const float* __restrict__ neb,
                                                const int* __restrict__ dkb, float* __restrict__ Cf) {
  __shared__ u16 As[64 * 64], Bs[64 * 64];   // 16 KB
  const int b = blockIdx.x;                   // 512 blocks
  const int g = (b & 7) * 64 + (b >> 3);      // bijective; 2 bn-panels per XCD
  const int bn = (g >> 5) * 64;
  const int bm = (g & 31) * 64;
  const int tid = threadIdx.x, w = tid >> 6, lane = tid & 63;
  const int lg = lane >> 4, l16 = lane & 15;
  if (b == 0 && w == 3) {                     // finalize scalars
    float s1 = 0.f, s2 = 0.f, s3 = 0.f;
    for (int i = lane; i < 512; i += 64) {
      float fdk = (float)dkb[i], kr = krb[i], ne = neb[i];
      float d2 = kr - ne;
      s1 += fdk; s2 += d2 * d2; s3 += kr;
    }
#pragma unroll
    for (int m = 1; m < 64; m <<= 1) {
      s1 += __shfl_xor(s1, m, 64);
      s2 += __shfl_xor(s2, m, 64);
      s3 += __shfl_xor(s3, m, 64);
    }
    if (lane == 0) {
      Cf[(size_t)kT * kHID + 0] = s1 * (1.f / 512.f);
      Cf[(size_t)kT * kHID + 1] = 0.01f * (s2 * (1.f / 512.f)) + 0.01f * (s3 * (1.f / 512.f));
    }
  }
  v4f acc[4] = {};
  for (int k0 = 0; k0 < kHID; k0 += 64) {
    __syncthreads();
#pragma unroll
    for (int p = 0; p < 2; ++p) {
      int s = tid + p * 256, row = s >> 3, sf = (s & 7) ^ (row & 7);
      gl_lds16(A + (size_t)(bm + row) * kHID + k0 + sf * 8, (char*)As + s * 16);
      gl_lds16(Bt + (size_t)(bn + row) * kHID + k0 + sf * 8, (char*)Bs + s * 16);
    }
    __syncthreads();
#pragma unroll
    for (int kk = 0; kk < 2; ++kk) {
      int row = w * 16 + l16;
      v8s a = *(const v8s*)((const char*)As + row * 128 + (((kk * 4 + lg) ^ (row & 7)) * 16));
#pragma unroll
      for (int j = 0; j < 4; ++j) {
        int col = j * 16 + l16;
        v8s bb = *(const v8s*)((const char*)Bs + col * 128 + (((kk * 4 + lg) ^ (col & 7)) * 16));
        acc[j] = mfma16(a, bb, acc[j]);
      }
    }
  }
#pragma unroll
  for (int j = 0; j < 4; ++j)
#pragma unroll
    for (int r = 0; r < 4; ++r) {
      int row = bm + w * 16 + lg * 4 + r;
      int col = bn + j * 16 + l16;
      Cf[(size_t)row * kHID + col] = acc[j][r];
    }
}

// ---------------- launch ----------------
extern "C" void kernel_launch(void* const* d_in, const int* in_sizes, int n_in,
                              void* d_out, int out_size, void* d_ws, size_t ws_size,
                              hipStream_t stream) {
  const float* x      = (const float*)d_in[0];
  const float* Wq     = (const float*)d_in[1];
  const float* Wk     = (const float*)d_in[2];
  const float* Wv     = (const float*)d_in[3];
  const float* Wo     = (const float*)d_in[4];
  const float* Wc     = (const float*)d_in[5];
  const float* bc     = (const float*)d_in[6];
  const float* kscale = (const float*)d_in[7];
  const float* kbias  = (const float*)d_in[8];
  const float* Wsp    = (const float*)d_in[9];
  const float* bsp    = (const float*)d_in[10];
  float* out = (float*)d_out;
  char* W = (char*)d_ws;

  u16* qh     = (u16*)(W + 0 * MB);
  u16* kbf    = (u16*)(W + 8 * MB);
  u16* vbf    = (u16*)(W + 16 * MB);
  u16* merged = (u16*)(W + 20 * MB);
  u16* xh     = (u16*)(W + 24 * MB);
  u16* WqtH   = (u16*)(W + 32 * MB);
  u16* WktH   = (u16*)(W + 36 * MB);
  u16* WvtH   = (u16*)(W + 40 * MB);
  u16* WotH   = (u16*)(W + 42 * MB);
  u16* WctH   = (u16*)(W + 44 * MB);
  u16* WctL   = (u16*)(W + 44 * MB + 512 * 1024);
  u16* Wst    = (u16*)(W + 45 * MB);          // 256 KB (padded 128x1024)
  float* strat= (float*)(W + 46 * MB);
  float* Pk   = (float*)(W + 47 * MB);
  float* Pv   = (float*)(W + 48 * MB);
  float* krb  = (float*)(W + 49 * MB + 4 * 1024);
  float* neb  = (float*)(W + 49 * MB + 8 * 1024);
  int*   dkb  = (int*)(W + 49 * MB + 12 * 1024);

  dim3 b256(256);
  prep_kernel<<<5888, b256, 0, stream>>>(x, Wq, Wk, Wv, Wo, Wc, Wsp,
                                         xh, WqtH, WktH, WvtH, WotH, WctH, WctL, Wst);
  proj_gemm<<<800, b256, 0, stream>>>(xh, WktH, WqtH, WvtH, Wst,
                                      bsp, kbf, qh, vbf, strat);
  cgemm_fused<<<dim3(1, 8, 16), b256, 0, stream>>>(kbf, vbf, WctH, WctL, Pk, Pv);
  attn_fused<<<512, b256, 0, stream>>>(qh, kbf, vbf, Pk, Pv, bc, strat,
                                       kscale, kbias, krb, neb, dkb, merged);
  gemm_out<<<512, b256, 0, stream>>>(merged, WotH, krb, neb, dkb, out);
}

// Round 14
// 88.383 us; speedup vs baseline: 1.0074x; 1.0074x over previous
//
#include <hip/hip_runtime.h>
#include <math.h>
#include <stdint.h>

typedef unsigned short u16;
typedef short v8s __attribute__((ext_vector_type(8)));
typedef float v4f __attribute__((ext_vector_type(4)));

constexpr int kT   = 2048;
constexpr int kHID = 1024;
constexpr int kH   = 16;
constexpr int kNB  = 32;
constexpr size_t MB = 1ull << 20;

__device__ __forceinline__ float b2f(u16 u) { unsigned x = ((unsigned)u) << 16; return __uint_as_float(x); }
__device__ __forceinline__ u16 f2b(float f) {
  unsigned x = __float_as_uint(f);
  x += 0x7FFFu + ((x >> 16) & 1u);
  return (u16)(x >> 16);
}
__device__ __forceinline__ v4f mfma16(v8s a, v8s b, v4f c) {
  return __builtin_amdgcn_mfma_f32_16x16x32_bf16(a, b, c, 0, 0, 0);
}
__device__ __forceinline__ void gl_lds16(const void* g, void* l) {
  __builtin_amdgcn_global_load_lds((const __attribute__((address_space(1))) uint32_t*)g,
                                   (__attribute__((address_space(3))) uint32_t*)l, 16, 0, 0);
}

// ==== fused prep: x->bf16, Wq/Wk/Wv/Wo/Wc transposes (bf16 hi only), Ws pad(128) ====
__global__ __launch_bounds__(256) void prep_kernel(
    const float* __restrict__ x, const float* __restrict__ Wq, const float* __restrict__ Wk,
    const float* __restrict__ Wv, const float* __restrict__ Wo, const float* __restrict__ Wc,
    const float* __restrict__ Wsp,
    u16* __restrict__ xh,
    u16* __restrict__ WqtH, u16* __restrict__ WktH,
    u16* __restrict__ WvtH, u16* __restrict__ WotH, u16* __restrict__ WctH,
    u16* __restrict__ Wst) {
  __shared__ float tbuf[32][33];
  int bid = blockIdx.x;
  const int tid = threadIdx.x;
  if (bid < 1024) {                        // x -> bf16: 8 elems/thread
    int i = bid * 2048 + tid * 8;
    float4 a = *(const float4*)(x + i), b = *(const float4*)(x + i + 4);
    float tv[8] = {a.x, a.y, a.z, a.w, b.x, b.y, b.z, b.w};
    union { u16 s[8]; uint4 u; } hs;
#pragma unroll
    for (int e = 0; e < 8; ++e) hs.s[e] = f2b(tv[e]);
    *(uint4*)(xh + i) = hs.u;
    return;
  }
  bid -= 1024;
  const float* W; u16* Hh; int Kd, Nd, bx, by;
  if (bid < 4096) {                        // 1024x1024 weight transposes
    int wsel = bid >> 10, sub = bid & 1023;
    W  = wsel == 0 ? Wq : wsel == 1 ? Wk : wsel == 2 ? Wv : Wo;
    Hh = wsel == 0 ? WqtH : wsel == 1 ? WktH : wsel == 2 ? WvtH : WotH;
    Kd = 1024; Nd = 1024;
    bx = (sub & 31) * 32; by = (sub >> 5) * 32;
  } else if (bid < 4096 + 256) {           // Wc (4096x64)
    int sub = bid - 4096;
    W = Wc; Hh = WctH;
    Kd = 4096; Nd = 64;
    bx = (sub & 1) * 32; by = (sub >> 1) * 32;
  } else {                                 // Wst pad: 128x1024
    int i = (bid - 4096 - 256) * 256 + tid;
    int n = i >> 10, k2 = i & 1023;
    float v = (n < 48) ? Wsp[(size_t)k2 * 48 + n] : 0.f;
    Wst[(size_t)n * 1024 + k2] = f2b(v);
    return;
  }
  const int lx = tid & 31, ly = tid >> 5;
  for (int i2 = ly; i2 < 32; i2 += 8) tbuf[i2][lx] = W[(size_t)(by + i2) * Nd + bx + lx];
  __syncthreads();
  for (int i2 = ly; i2 < 32; i2 += 8) {
    float xv = tbuf[lx][i2];
    Hh[(size_t)(bx + i2) * Kd + by + lx] = f2b(xv);
  }
}

// ==== unified projection GEMM, single-combo bf16, BM=64 BN=128 BK=64 ====
__global__ __launch_bounds__(256) void proj_gemm(const u16* __restrict__ xh,
                                                 const u16* __restrict__ WkH, const u16* __restrict__ WqH,
                                                 const u16* __restrict__ WvH, const u16* __restrict__ Wst,
                                                 const float* __restrict__ bsp,
                                                 u16* __restrict__ kbf, u16* __restrict__ qh,
                                                 u16* __restrict__ vbf, float* __restrict__ strat) {
  __shared__ u16 AsH[64 * 64], BsH[128 * 64];   // 24 KB
  const int b = blockIdx.x;                      // 800 blocks
  const int slot = (b & 7) * 100 + (b >> 3);     // bijective [0,800)
  const int panel = slot >> 5, bmi = slot & 31;
  int z, bni;
  if (panel < 8)       { z = 0; bni = panel; }
  else if (panel < 16) { z = 1; bni = panel - 8; }
  else if (panel < 24) { z = 2; bni = panel - 16; }
  else                 { z = 3; bni = 0; }
  const int bm = bmi * 64, bn = bni * 128;
  const u16* Bh = (z == 0) ? WkH : (z == 1) ? WqH : (z == 2) ? WvH : Wst;
  const int tid = threadIdx.x, w = tid >> 6, lane = tid & 63;
  const int lg = lane >> 4, l16 = lane & 15;
  const int wr = w >> 1, wc = w & 1;
  v4f acc[2][4] = {};
  for (int k0 = 0; k0 < kHID; k0 += 64) {
    __syncthreads();
#pragma unroll
    for (int p = 0; p < 2; ++p) {
      int s = tid + p * 256, row = s >> 3, sf = (s & 7) ^ (row & 7);
      gl_lds16(xh + (size_t)(bm + row) * kHID + k0 + sf * 8, (char*)AsH + s * 16);
    }
#pragma unroll
    for (int p = 0; p < 4; ++p) {
      int s = tid + p * 256, row = s >> 3, sf = (s & 7) ^ (row & 7);
      gl_lds16(Bh + (size_t)(bn + row) * kHID + k0 + sf * 8, (char*)BsH + s * 16);
    }
    __syncthreads();
#pragma unroll
    for (int kk = 0; kk < 2; ++kk) {
      v8s bh4[4];
#pragma unroll
      for (int j = 0; j < 4; ++j) {
        int col = wc * 64 + j * 16 + l16;
        bh4[j] = *(const v8s*)((const char*)BsH + col * 128 + (((kk * 4 + lg) ^ (col & 7)) * 16));
      }
#pragma unroll
      for (int i = 0; i < 2; ++i) {
        int row = wr * 32 + i * 16 + l16;
        v8s ah = *(const v8s*)((const char*)AsH + row * 128 + (((kk * 4 + lg) ^ (row & 7)) * 16));
#pragma unroll
        for (int j = 0; j < 4; ++j) acc[i][j] = mfma16(ah, bh4[j], acc[i][j]);
      }
    }
  }
#pragma unroll
  for (int i = 0; i < 2; ++i)
#pragma unroll
    for (int j = 0; j < 4; ++j)
#pragma unroll
      for (int r = 0; r < 4; ++r) {
        int row = bm + wr * 32 + i * 16 + lg * 4 + r;
        int col = bn + wc * 64 + j * 16 + l16;
        float val = acc[i][j][r];
        if (z == 3) {
          if (col < 48) strat[(size_t)row * 48 + col] = 1.f / (1.f + expf(-(val + bsp[col])));
        } else {
          u16 hh = f2b(val);
          size_t idx = (size_t)row * kHID + col;
          if (z == 0) kbf[idx] = hh;
          else if (z == 1) qh[idx] = hh;
          else vbf[idx] = hh;
        }
      }
}

// ==== compress GEMM: single-combo both paths; split-K partials ====
__global__ __launch_bounds__(256) void cgemm_fused(const u16* __restrict__ kbf,
                                                   const u16* __restrict__ vbf,
                                                   const u16* __restrict__ WcH,
                                                   float* __restrict__ Pk, float* __restrict__ Pv) {
  __shared__ u16 AsH[64 * 64], BsH[64 * 64];   // 16 KB
  const int bm = blockIdx.y * 64;
  const int isK = (blockIdx.z < 8);
  const int ks = isK ? blockIdx.z : blockIdx.z - 8;
  const u16* Asrc = isK ? kbf : vbf;
  float* P = isK ? Pk : Pv;
  const int tid = threadIdx.x;
  const int w = tid >> 6, lane = tid & 63;
  const int lg = lane >> 4, l16 = lane & 15;
  const int wr = w >> 1, wc = w & 1;
  v4f acc[2][2] = {};
  for (int k0 = ks * 512; k0 < ks * 512 + 512; k0 += 64) {
    __syncthreads();
#pragma unroll
    for (int ss = 0; ss < 2; ++ss) {
      int s = tid + ss * 256, row = s >> 3, sf = (s & 7) ^ (row & 7);
      int r = bm + row;                              // (h*32+nb)
      size_t abase = ((size_t)((r & 31) * 64 + (k0 >> 6))) * kHID + (r >> 5) * 64 + sf * 8;
      gl_lds16(Asrc + abase, (char*)AsH + s * 16);
      gl_lds16(WcH + (size_t)row * 4096 + k0 + sf * 8, (char*)BsH + s * 16);
    }
    __syncthreads();
    v8s ah[2][2], bh[2][2];
#pragma unroll
    for (int i = 0; i < 2; ++i)
#pragma unroll
      for (int kk = 0; kk < 2; ++kk) {
        int row = wr * 32 + i * 16 + l16;
        ah[i][kk] = *(const v8s*)((const char*)AsH + row * 128 + (((kk * 4 + lg) ^ (row & 7)) * 16));
        int col = wc * 32 + i * 16 + l16;
        bh[i][kk] = *(const v8s*)((const char*)BsH + col * 128 + (((kk * 4 + lg) ^ (col & 7)) * 16));
      }
#pragma unroll
    for (int i = 0; i < 2; ++i)
#pragma unroll
      for (int j = 0; j < 2; ++j) {
        acc[i][j] = mfma16(ah[i][0], bh[j][0], acc[i][j]);
        acc[i][j] = mfma16(ah[i][1], bh[j][1], acc[i][j]);
      }
  }
#pragma unroll
  for (int i = 0; i < 2; ++i)
#pragma unroll
    for (int j = 0; j < 2; ++j)
#pragma unroll
      for (int r = 0; r < 4; ++r) {
        int row = bm + wr * 32 + i * 16 + lg * 4 + r;
        int col = wc * 32 + j * 16 + l16;
        P[(size_t)ks * 32768 + (size_t)row * 64 + col] = acc[i][j][r];
      }
}

// ==== fused attention: reduce+GELU + importance + comp + selection + fine + slide ====
// diagonal K-tile staged at kernel start (always selected) -> overlaps phase A
__global__ __launch_bounds__(256) void attn_fused(const u16* __restrict__ qh,
                                                  const u16* __restrict__ kb_,
                                                  const u16* __restrict__ vb_,
                                                  const float* __restrict__ Pk,
                                                  const float* __restrict__ Pv,
                                                  const float* __restrict__ bc,
                                                  const float* __restrict__ strat,
                                                  const float* __restrict__ kscale_p,
                                                  const float* __restrict__ kbias_p,
                                                  float* __restrict__ krb,
                                                  float* __restrict__ neb,
                                                  int* __restrict__ dkb,
                                                  u16* __restrict__ merged) {
  __shared__ char smem[51200] __attribute__((aligned(128)));
  const int b = blockIdx.x;
  const int xcd = b & 7, slot = b >> 3;
  const int h = xcd + 8 * (slot >> 5);     // head-colocated per XCD
  const int qb = slot & 31;
  const int tid = threadIdx.x, w = tid >> 6, lane = tid & 63;
  const int lg = lane >> 4, l16 = lane & 15;

  // LDS layout: phase A = [0,17K); phase B: PlB=[0,8K) (reused), KbB=[18K,34K), VtB=[34K,50K)
  char* KCH = smem;                    // 4 KB
  char* KCL = smem + 4096;             // 4 KB
  char* VCT = smem + 8192;             // 4 KB
  u16*  PlA = (u16*)(smem + 12288);    // 4 KB
  float* red = (float*)(smem + 16384); // 512 B
  unsigned* mshare = (unsigned*)(smem + 16896);
  char* PlB = smem;                    // 8 KB (after phase A done)
  char* KbB = smem + 18432;            // 2 x 8 KB
  char* VtB = smem + 34816;            // 2 x 8 KB

  const int vkey = tid & 63, vd0 = (tid >> 6) * 16;
  auto k_stage = [&](int buf, int jb) {
#pragma unroll
    for (int ss = 0; ss < 2; ++ss) {
      int s = tid + ss * 256;
      int key = s >> 3, sf = (s & 7) ^ (key & 7);
      gl_lds16(kb_ + (size_t)(jb * 64 + key) * kHID + h * 64 + sf * 8, KbB + buf * 8192 + s * 16);
    }
  };
  auto v_issue = [&](int jb, uint4& c0, uint4& c1) {
    const u16* vsrc = vb_ + (size_t)(jb * 64 + vkey) * kHID + h * 64 + vd0;
    c0 = *(const uint4*)(vsrc);
    c1 = *(const uint4*)(vsrc + 8);
  };
  auto v_write = [&](int buf, uint4 c0, uint4 c1) {
    union { uint4 u[2]; u16 s[16]; } c;
    c.u[0] = c0; c.u[1] = c1;
#pragma unroll
    for (int i = 0; i < 16; ++i) {
      int d = vd0 + i;
      *((u16*)(VtB + buf * 8192 + d * 128 + (((vkey >> 3) ^ (d & 7)) * 16)) + (vkey & 7)) = c.s[i];
    }
  };

  // ---- early prologue: stage diagonal tile (always selected); overlaps phase A ----
  uint4 vc0, vc1;
  k_stage(0, qb);
  v_issue(qb, vc0, vc1);

  // ======== phase A: split-K reduce + GELU + importance + comp + selection ========
  {
    int nb = tid >> 3, seg = tid & 7;
    {
      const float* base = Pk + ((size_t)(h * 32 + nb) * 64 + seg * 8);
      float v[8] = {};
#pragma unroll
      for (int ks = 0; ks < 8; ++ks) {
        const float* p = base + (size_t)ks * 32768;
        float4 a = *(const float4*)p, bq = *(const float4*)(p + 4);
        v[0] += a.x; v[1] += a.y; v[2] += a.z; v[3] += a.w;
        v[4] += bq.x; v[5] += bq.y; v[6] += bq.z; v[7] += bq.w;
      }
      v8s hi, lo;
#pragma unroll
      for (int e = 0; e < 8; ++e) {
        float s = v[e] + bc[seg * 8 + e];
        float g = 0.5f * s * (1.f + erff(s * 0.70710678118654752f));
        u16 hh = f2b(g);
        hi[e] = (short)hh;
        lo[e] = (short)f2b(g - b2f(hh));
      }
      *(v8s*)(KCH + nb * 128 + ((seg ^ (nb & 7)) * 16)) = hi;
      *(v8s*)(KCL + nb * 128 + ((seg ^ (nb & 7)) * 16)) = lo;
    }
    {
      const float* base = Pv + ((size_t)(h * 32 + nb) * 64 + seg * 8);
      float v[8] = {};
#pragma unroll
      for (int ks = 0; ks < 8; ++ks) {
        const float* p = base + (size_t)ks * 32768;
        float4 a = *(const float4*)p, bq = *(const float4*)(p + 4);
        v[0] += a.x; v[1] += a.y; v[2] += a.z; v[3] += a.w;
        v[4] += bq.x; v[5] += bq.y; v[6] += bq.z; v[7] += bq.w;
      }
#pragma unroll
      for (int e = 0; e < 8; ++e) {
        int d = seg * 8 + e;
        float s = v[e] + bc[d];
        float g = 0.5f * s * (1.f + erff(s * 0.70710678118654752f));
        *((u16*)(VCT + d * 64 + (((nb >> 3) ^ (d & 3)) * 16) + (nb & 7) * 2)) = f2b(g);
      }
    }
  }
  // prefetch strat gates for epilogue
  float st0r[4], st1r[4], st2r[4];
#pragma unroll
  for (int j = 0; j < 4; ++j) {
    int t = qb * 64 + w * 16 + lg * 4 + j;
    st0r[j] = strat[t * 48 + h * 3 + 0];
    st1r[j] = strat[t * 48 + h * 3 + 1];
    st2r[j] = strat[t * 48 + h * 3 + 2];
  }
  __syncthreads();
  const size_t qoff = (size_t)(qb * 64 + w * 16 + l16) * kHID + h * 64;
  v8s aq[2];
  aq[0] = *(const v8s*)(qh + qoff + lg * 8);
  aq[1] = *(const v8s*)(qh + qoff + 32 + lg * 8);
  v4f sa2[2] = {};
#pragma unroll
  for (int ct = 0; ct < 2; ++ct) {
    int col = ct * 16 + l16;
#pragma unroll
    for (int kk = 0; kk < 2; ++kk) {
      int bo = col * 128 + (((kk * 4 + lg) ^ (col & 7)) * 16);
      v8s bh = *(const v8s*)(KCH + bo);
      v8s bl = *(const v8s*)(KCL + bo);
      sa2[ct] = mfma16(aq[kk], bh, sa2[ct]);
      sa2[ct] = mfma16(aq[kk], bl, sa2[ct]);
    }
  }
#pragma unroll
  for (int ct = 0; ct < 2; ++ct)
#pragma unroll
    for (int j = 0; j < 4; ++j) sa2[ct][j] *= 0.125f;
#pragma unroll
  for (int ct = 0; ct < 2; ++ct) {
    float v = sa2[ct][0] + sa2[ct][1] + sa2[ct][2] + sa2[ct][3];
    v += __shfl_xor(v, 16, 64);
    v += __shfl_xor(v, 32, 64);
    if (lg == 0) red[w * 32 + ct * 16 + l16] = v;
  }
  float linv[4];
#pragma unroll
  for (int j = 0; j < 4; ++j) {
    float m = fmaxf(sa2[0][j], sa2[1][j]);
#pragma unroll
    for (int mm = 1; mm < 16; mm <<= 1) m = fmaxf(m, __shfl_xor(m, mm, 64));
    float e0 = __expf(sa2[0][j] - m), e1 = __expf(sa2[1][j] - m);
    float s = e0 + e1;
#pragma unroll
    for (int mm = 1; mm < 16; mm <<= 1) s += __shfl_xor(s, mm, 64);
    linv[j] = 1.f / s;
    int row = lg * 4 + j;
    PlA[w * 512 + row * 32 + l16] = f2b(e0);
    PlA[w * 512 + row * 32 + 16 + l16] = f2b(e1);
  }
  v8s pca = *(const v8s*)(PlA + w * 512 + l16 * 32 + lg * 8);
  float compC[4][4];
  {
    v4f o[4];
#pragma unroll
    for (int dt = 0; dt < 4; ++dt) {
      int d = dt * 16 + l16;
      v8s bb = *(const v8s*)(VCT + d * 64 + ((lg ^ (d & 3)) * 16));
      v4f z = {};
      o[dt] = mfma16(pca, bb, z);
#pragma unroll
      for (int j = 0; j < 4; ++j) compC[dt][j] = o[dt][j] * linv[j];
    }
  }
  // diagonal V tile -> LDS (VtB disjoint from phase A regions)
  v_write(0, vc0, vc1);
  __syncthreads();
  // selection by wave 0 -> mword broadcast
  if (w == 0) {
    const int j = lane & 31;
    float bsj = (red[j] + red[32 + j] + red[64 + j] + red[96 + j]) * (1.f / 64.f);
    float mx = bsj;
#pragma unroll
    for (int m = 1; m < 32; m <<= 1) mx = fmaxf(mx, __shfl_xor(mx, m, 64));
    float e = expf(bsj - mx);
    float lsum = e;
#pragma unroll
    for (int m = 1; m < 32; m <<= 1) lsum += __shfl_xor(lsum, m, 64);
    float p = e / lsum;
    float ent = p * logf(p + 1e-9f);
#pragma unroll
    for (int m = 1; m < 32; m <<= 1) ent += __shfl_xor(ent, m, 64);
    ent = -ent;
    float ne = ent / (logf(32.f) + 1e-9f);
    float kr = 1.f / (1.f + expf(-(kscale_p[0] * ne + kbias_p[0])));
    int dk = (int)fminf(fmaxf(8.f * kr, 1.f), 8.f);
    unsigned mword = 1u << qb;
    int taken = 0;
    for (int r = 0; r < dk; ++r) {
      float v2 = taken ? -3.4e38f : bsj;
      int idx2 = j;
#pragma unroll
      for (int m = 1; m < 32; m <<= 1) {
        float ov = __shfl_xor(v2, m, 64);
        int oi = __shfl_xor(idx2, m, 64);
        if (ov > v2 || (ov == v2 && oi < idx2)) { v2 = ov; idx2 = oi; }
      }
      mword |= (1u << idx2);
      if (j == idx2) taken = 1;
    }
    if (lane == 0) {
      krb[h * kNB + qb] = kr;
      neb[h * kNB + qb] = ne;
      dkb[h * kNB + qb] = dk;
      *mshare = mword;
    }
  }
  __syncthreads();
  const unsigned mword = *mshare;
  __syncthreads();   // all reads of phase-A LDS done; PlB region reusable

  // ======== phase B: fine + slide, diag-first walk ========
  unsigned uni = mword | (1u << qb);
  if (qb > 0) uni |= 1u << (qb - 1);
  float mF[4], lF[4], mS[4], lS[4];
  v4f oF[4] = {}, oS[4] = {};
#pragma unroll
  for (int j = 0; j < 4; ++j) { mF[j] = -1e30f; lF[j] = 0.f; mS[j] = -1e30f; lS[j] = 0.f; }

  auto upd = [&](const v4f* sa, float* m_run, float* l_run, v4f* o_acc, int buf) {
    float corr[4];
#pragma unroll
    for (int j = 0; j < 4; ++j) {
      float t = fmaxf(fmaxf(sa[0][j], sa[1][j]), fmaxf(sa[2][j], sa[3][j]));
#pragma unroll
      for (int mm = 1; mm < 16; mm <<= 1) t = fmaxf(t, __shfl_xor(t, mm, 64));
      float mn = fmaxf(m_run[j], t);
      corr[j] = __expf(m_run[j] - mn);
      m_run[j] = mn;
    }
    float rs[4] = {0.f, 0.f, 0.f, 0.f};
    float pv[4][4];
#pragma unroll
    for (int ct = 0; ct < 4; ++ct)
#pragma unroll
      for (int j = 0; j < 4; ++j) {
        float e = __expf(sa[ct][j] - m_run[j]);
        pv[ct][j] = e;
        rs[j] += e;
      }
#pragma unroll
    for (int j = 0; j < 4; ++j) {
#pragma unroll
      for (int mm = 1; mm < 16; mm <<= 1) rs[j] += __shfl_xor(rs[j], mm, 64);
      l_run[j] = l_run[j] * corr[j] + rs[j];
    }
#pragma unroll
    for (int ct = 0; ct < 4; ++ct)
#pragma unroll
      for (int j = 0; j < 4; ++j) {
        int row = lg * 4 + j;
        int seg = ct * 2 + (l16 >> 3);
        *((u16*)(PlB + w * 2048 + row * 128 + ((seg ^ (row & 7)) * 16)) + (l16 & 7)) = f2b(pv[ct][j]);
      }
#pragma unroll
    for (int dt = 0; dt < 4; ++dt)
#pragma unroll
      for (int j = 0; j < 4; ++j) o_acc[dt][j] *= corr[j];
#pragma unroll
    for (int dt = 0; dt < 4; ++dt) {
      int d = dt * 16 + l16;
#pragma unroll
      for (int kk = 0; kk < 2; ++kk) {
        v8s pa = *(const v8s*)(PlB + w * 2048 + l16 * 128 + (((kk * 4 + lg) ^ (l16 & 7)) * 16));
        v8s vb2 = *(const v8s*)(VtB + buf * 8192 + d * 128 + (((kk * 4 + lg) ^ (d & 7)) * 16));
        o_acc[dt] = mfma16(pa, vb2, o_acc[dt]);
      }
    }
  };

  int jb_cur = qb;                          // diagonal first (already staged in buf 0)
  unsigned rem = uni & ~(1u << qb);
  int buf = 0;
  while (jb_cur >= 0) {
    int jb_next = -1;
    if (rem) { jb_next = __builtin_ctz(rem); rem &= rem - 1; }
    __syncthreads();                        // tile (jb_cur, buf) fully staged
    if (jb_next >= 0) { v_issue(jb_next, vc0, vc1); k_stage(buf ^ 1, jb_next); }
    v4f sa[4] = {};
#pragma unroll
    for (int ct = 0; ct < 4; ++ct) {
      int key = ct * 16 + l16;
#pragma unroll
      for (int kk = 0; kk < 2; ++kk) {
        v8s bk = *(const v8s*)(KbB + buf * 8192 + key * 128 + (((kk * 4 + lg) ^ (key & 7)) * 16));
        sa[ct] = mfma16(aq[kk], bk, sa[ct]);
      }
    }
#pragma unroll
    for (int ct = 0; ct < 4; ++ct)
#pragma unroll
      for (int j = 0; j < 4; ++j) sa[ct][j] *= 0.125f;
    const bool inF = (mword >> jb_cur) & 1u;
    const bool inS = (jb_cur == qb) || (jb_cur + 1 == qb);
    if (inF) upd(sa, mF, lF, oF, buf);
    if (inS) {
      v4f sb[4];
#pragma unroll
      for (int ct = 0; ct < 4; ++ct) sb[ct] = sa[ct];
      if (jb_cur == qb) {
#pragma unroll
        for (int ct = 0; ct < 4; ++ct) {
          int key = ct * 16 + l16;
#pragma unroll
          for (int j = 0; j < 4; ++j) {
            int qp = w * 16 + lg * 4 + j;
            if (key > qp) sb[ct][j] = -1e30f;
          }
        }
      }
      upd(sb, mS, lS, oS, buf);
    }
    if (jb_next >= 0) v_write(buf ^ 1, vc0, vc1);
    jb_cur = jb_next;
    buf ^= 1;
  }
  // epilogue: merged = st0*slide + st1*comp + st2*fine (single store)
#pragma unroll
  for (int j = 0; j < 4; ++j) {
    int t = qb * 64 + w * 16 + lg * 4 + j;
    float invS = 1.f / lS[j], invF = 1.f / lF[j];
#pragma unroll
    for (int dt = 0; dt < 4; ++dt) {
      int d = dt * 16 + l16;
      size_t idx = (size_t)t * kHID + h * 64 + d;
      float val = st0r[j] * (oS[dt][j] * invS) + st1r[j] * compC[dt][j] + st2r[j] * (oF[dt][j] * invF);
      merged[idx] = f2b(val);
    }
  }
}

// ==== output projection + finalize scalars: BM=64 BN=64, 512 blocks ====
__global__ __launch_bounds__(256) void gemm_out(const u16* __restrict__ A, const u16* __restrict__ Bt,
                                                const float* __restrict__ krb, const float* __restrict__ neb,
                                                const int* __restrict__ dkb, float* __restrict__ Cf) {
  __shared__ u16 As[64 * 64], Bs[64 * 64];   // 16 KB
  const int b = blockIdx.x;                   // 512 blocks
  const int g = (b & 7) * 64 + (b >> 3);      // bijective; 2 bn-panels per XCD
  const int bn = (g >> 5) * 64;
  const int bm = (g & 31) * 64;
  const int tid = threadIdx.x, w = tid >> 6, lane = tid & 63;
  const int lg = lane >> 4, l16 = lane & 15;
  if (b == 0 && w == 3) {                     // finalize scalars
    float s1 = 0.f, s2 = 0.f, s3 = 0.f;
    for (int i = lane; i < 512; i += 64) {
      float fdk = (float)dkb[i], kr = krb[i], ne = neb[i];
      float d2 = kr - ne;
      s1 += fdk; s2 += d2 * d2; s3 += kr;
    }
#pragma unroll
    for (int m = 1; m < 64; m <<= 1) {
      s1 += __shfl_xor(s1, m, 64);
      s2 += __shfl_xor(s2, m, 64);
      s3 += __shfl_xor(s3, m, 64);
    }
    if (lane == 0) {
      Cf[(size_t)kT * kHID + 0] = s1 * (1.f / 512.f);
      Cf[(size_t)kT * kHID + 1] = 0.01f * (s2 * (1.f / 512.f)) + 0.01f * (s3 * (1.f / 512.f));
    }
  }
  v4f acc[4] = {};
  for (int k0 = 0; k0 < kHID; k0 += 64) {
    __syncthreads();
#pragma unroll
    for (int p = 0; p < 2; ++p) {
      int s = tid + p * 256, row = s >> 3, sf = (s & 7) ^ (row & 7);
      gl_lds16(A + (size_t)(bm + row) * kHID + k0 + sf * 8, (char*)As + s * 16);
      gl_lds16(Bt + (size_t)(bn + row) * kHID + k0 + sf * 8, (char*)Bs + s * 16);
    }
    __syncthreads();
#pragma unroll
    for (int kk = 0; kk < 2; ++kk) {
      int row = w * 16 + l16;
      v8s a = *(const v8s*)((const char*)As + row * 128 + (((kk * 4 + lg) ^ (row & 7)) * 16));
#pragma unroll
      for (int j = 0; j < 4; ++j) {
        int col = j * 16 + l16;
        v8s bb = *(const v8s*)((const char*)Bs + col * 128 + (((kk * 4 + lg) ^ (col & 7)) * 16));
        acc[j] = mfma16(a, bb, acc[j]);
      }
    }
  }
#pragma unroll
  for (int j = 0; j < 4; ++j)
#pragma unroll
    for (int r = 0; r < 4; ++r) {
      int row = bm + w * 16 + lg * 4 + r;
      int col = bn + j * 16 + l16;
      Cf[(size_t)row * kHID + col] = acc[j][r];
    }
}

// ---------------- launch ----------------
extern "C" void kernel_launch(void* const* d_in, const int* in_sizes, int n_in,
                              void* d_out, int out_size, void* d_ws, size_t ws_size,
                              hipStream_t stream) {
  const float* x      = (const float*)d_in[0];
  const float* Wq     = (const float*)d_in[1];
  const float* Wk     = (const float*)d_in[2];
  const float* Wv     = (const float*)d_in[3];
  const float* Wo     = (const float*)d_in[4];
  const float* Wc     = (const float*)d_in[5];
  const float* bc     = (const float*)d_in[6];
  const float* kscale = (const float*)d_in[7];
  const float* kbias  = (const float*)d_in[8];
  const float* Wsp    = (const float*)d_in[9];
  const float* bsp    = (const float*)d_in[10];
  float* out = (float*)d_out;
  char* W = (char*)d_ws;

  u16* qh     = (u16*)(W + 0 * MB);
  u16* kbf    = (u16*)(W + 8 * MB);
  u16* vbf    = (u16*)(W + 16 * MB);
  u16* merged = (u16*)(W + 20 * MB);
  u16* xh     = (u16*)(W + 24 * MB);
  u16* WqtH   = (u16*)(W + 32 * MB);
  u16* WktH   = (u16*)(W + 36 * MB);
  u16* WvtH   = (u16*)(W + 40 * MB);
  u16* WotH   = (u16*)(W + 42 * MB);
  u16* WctH   = (u16*)(W + 44 * MB);
  u16* Wst    = (u16*)(W + 45 * MB);          // 256 KB (padded 128x1024)
  float* strat= (float*)(W + 46 * MB);
  float* Pk   = (float*)(W + 47 * MB);
  float* Pv   = (float*)(W + 48 * MB);
  float* krb  = (float*)(W + 49 * MB + 4 * 1024);
  float* neb  = (float*)(W + 49 * MB + 8 * 1024);
  int*   dkb  = (int*)(W + 49 * MB + 12 * 1024);

  dim3 b256(256);
  prep_kernel<<<5888, b256, 0, stream>>>(x, Wq, Wk, Wv, Wo, Wc, Wsp,
                                         xh, WqtH, WktH, WvtH, WotH, WctH, Wst);
  proj_gemm<<<800, b256, 0, stream>>>(xh, WktH, WqtH, WvtH, Wst,
                                      bsp, kbf, qh, vbf, strat);
  cgemm_fused<<<dim3(1, 8, 16), b256, 0, stream>>>(kbf, vbf, WctH, Pk, Pv);
  attn_fused<<<512, b256, 0, stream>>>(qh, kbf, vbf, Pk, Pv, bc, strat,
                                       kscale, kbias, krb, neb, dkb, merged);
  gemm_out<<<512, b256, 0, stream>>>(merged, WotH, krb, neb, dkb, out);
}